// Round 13
// baseline (803.277 us; speedup 1.0000x reference)
//
#include <hip/hip_runtime.h>
#include <hip/hip_bf16.h>

#define N_NODES 50000
#define MP 50048            // padded row count (multiple of 128)
#define N_EDGES 800000
#define N_B 128
#define H_DIM 256
#define H2_DIM 512
#define FIN_DIM 8
#define GF_DIM 85
#define LN_EPS 1e-5f
#define SCAN_NBLK 196       // ceil(50000/256)

typedef unsigned short u16;
typedef unsigned int u32;
typedef _Float16 f16;
typedef __attribute__((ext_vector_type(8))) _Float16 f16x8;
typedef __attribute__((ext_vector_type(8))) unsigned short u16x8;
typedef __attribute__((ext_vector_type(4))) float f32x4;

__device__ inline float relu_f(float x) { return x > 0.f ? x : 0.f; }

__device__ inline float h2f(u16 b) { f16 h; __builtin_memcpy(&h, &b, 2); return (float)h; }
__device__ inline u16 f2h(float x) { f16 h = (f16)x; u16 b; __builtin_memcpy(&b, &h, 2); return b; }

#define GLOAD16(gp, lp) __builtin_amdgcn_global_load_lds( \
    (const __attribute__((address_space(1))) void*)(gp),  \
    (__attribute__((address_space(3))) void*)(lp), 16, 0, 0)

// LayerNorm stats across a 256-thread block (one value per thread)
__device__ inline void ln_stats_256(float v, float* sbuf, float& mean, float& rstd) {
    float s = v, s2 = v * v;
#pragma unroll
    for (int off = 32; off > 0; off >>= 1) {
        s += __shfl_down(s, off);
        s2 += __shfl_down(s2, off);
    }
    int t = threadIdx.x;
    if ((t & 63) == 0) { sbuf[t >> 6] = s; sbuf[4 + (t >> 6)] = s2; }
    __syncthreads();
    float ts = sbuf[0] + sbuf[1] + sbuf[2] + sbuf[3];
    float ts2 = sbuf[4] + sbuf[5] + sbuf[6] + sbuf[7];
    mean = ts * (1.f / H_DIM);
    float var = ts2 * (1.f / H_DIM) - mean * mean;
    rstd = rsqrtf(var + LN_EPS);
}

// --- input projection: h = relu(LN(x @ W_in + b_in)), split-fp16 out ---------
__global__ void k_input_proj(const float* __restrict__ x, const float* __restrict__ Wi,
                             const float* __restrict__ bi, const float* __restrict__ g,
                             const float* __restrict__ bb,
                             u16* __restrict__ Hh, u16* __restrict__ Hl) {
    int n = blockIdx.x, t = threadIdx.x;
    __shared__ float xs[FIN_DIM];
    __shared__ float sbuf[8];
    if (t < FIN_DIM) xs[t] = x[n * FIN_DIM + t];
    __syncthreads();
    float acc = bi[t];
#pragma unroll
    for (int k = 0; k < FIN_DIM; ++k) acc = fmaf(xs[k], Wi[k * H_DIM + t], acc);
    float mean, rstd;
    ln_stats_256(acc, sbuf, mean, rstd);
    float v = relu_f(g[t] * (acc - mean) * rstd + bb[t]);
    u16 hh = f2h(v);
    size_t o = (size_t)n * H_DIM + t;
    Hh[o] = hh;
    Hl[o] = f2h(v - h2f(hh));
}

// ---------------- CSR build ---------------------------------------------------
__global__ void k_hist(const int* __restrict__ ei, int* __restrict__ deg) {
    int e = blockIdx.x * 256 + threadIdx.x;
    atomicAdd(&deg[ei[N_EDGES + e]], 1);
}

// 3-stage parallel exclusive scan of deg -> row_start
__global__ void k_scan1(const int* __restrict__ deg, int* __restrict__ row_start,
                        int* __restrict__ bsum) {
    __shared__ int s[256];
    int t = threadIdx.x, i = blockIdx.x * 256 + t;
    int v = (i < N_NODES) ? deg[i] : 0;
    s[t] = v;
    __syncthreads();
    for (int off = 1; off < 256; off <<= 1) {
        int x = (t >= off) ? s[t - off] : 0;
        __syncthreads();
        s[t] += x;
        __syncthreads();
    }
    if (i < N_NODES) row_start[i] = s[t] - v;  // exclusive within block
    if (t == 255) bsum[blockIdx.x] = s[255];
}

__global__ void k_scan2(int* __restrict__ bsum) {
    __shared__ int s[256];
    int t = threadIdx.x;
    int v = (t < SCAN_NBLK) ? bsum[t] : 0;
    s[t] = v;
    __syncthreads();
    for (int off = 1; off < 256; off <<= 1) {
        int x = (t >= off) ? s[t - off] : 0;
        __syncthreads();
        s[t] += x;
        __syncthreads();
    }
    if (t < SCAN_NBLK) bsum[t] = s[t] - v;  // exclusive block offsets
}

__global__ void k_scan3(int* __restrict__ row_start, const int* __restrict__ bsum) {
    int t = threadIdx.x, i = blockIdx.x * 256 + t;
    if (i < N_NODES) row_start[i] += bsum[blockIdx.x];
    if (i == 0) row_start[N_NODES] = N_EDGES;
}

// packed CSR payload: one 8B struct {w_bits, src} -> ONE random store per edge
__global__ void k_scatter(const int* __restrict__ ei, const float* __restrict__ ew,
                          const int* __restrict__ row_start, int* __restrict__ cursor,
                          uint2* __restrict__ csr_pk) {
    int e = blockIdx.x * 256 + threadIdx.x;
    int d = ei[N_EDGES + e];
    int p = atomicAdd(&cursor[d], 1);
    int i = row_start[d] + p;
    uint2 pk;
    pk.x = __float_as_uint(ew[e]);
    pk.y = (u32)ei[e];
    csr_pk[i] = pk;
}

// batch is sorted: graph b occupies [gstart[b], gstart[b+1])  — binary search
__global__ void k_gbounds(const int* __restrict__ batch, int* __restrict__ gstart,
                          int* __restrict__ gcnt) {
    __shared__ int s[N_B + 1];
    int b = threadIdx.x;  // 0..127
    int lo = 0, hi = N_NODES;
    while (lo < hi) {
        int mid = (lo + hi) >> 1;
        if (batch[mid] < b) lo = mid + 1; else hi = mid;
    }
    s[b] = lo;
    if (b == 0) s[N_B] = N_NODES;
    __syncthreads();
    gstart[b] = s[b];
    gcnt[b] = s[b + 1] - s[b];
}

// ---- GIN aggregation: A = fp16( (2+eps)*h + sum_in w*Hh[src] ) ---------------
// half-wave per node (avg degree 16); 8-deep unrolled gather prefetch.
__global__ void k_agg(const u16* __restrict__ Hh, const u16* __restrict__ Hl,
                      const int* __restrict__ row_start,
                      const uint2* __restrict__ csr_pk,
                      const float* __restrict__ eps, int layer,
                      u16* __restrict__ Ah) {
    const int t = threadIdx.x;
    const int n = blockIdx.x * 8 + (t >> 5);
    const int sl = t & 31;
    int start = row_start[n], end = row_start[n + 1];
    float a[8];
#pragma unroll
    for (int q = 0; q < 8; ++q) a[q] = 0.f;
    int e = start;
    for (; e + 7 < end; e += 8) {
        uint2 pk[8];
        u16x8 vv[8];
#pragma unroll
        for (int d = 0; d < 8; ++d) pk[d] = csr_pk[e + d];
#pragma unroll
        for (int d = 0; d < 8; ++d)
            vv[d] = *reinterpret_cast<const u16x8*>(&Hh[(size_t)pk[d].y * H_DIM + sl * 8]);
#pragma unroll
        for (int d = 0; d < 8; ++d) {
            float w = __uint_as_float(pk[d].x);
#pragma unroll
            for (int q = 0; q < 8; ++q) a[q] = fmaf(w, h2f(vv[d][q]), a[q]);
        }
    }
    for (; e + 3 < end; e += 4) {
        uint2 p0 = csr_pk[e], p1 = csr_pk[e + 1], p2 = csr_pk[e + 2], p3 = csr_pk[e + 3];
        u16x8 v0 = *reinterpret_cast<const u16x8*>(&Hh[(size_t)p0.y * H_DIM + sl * 8]);
        u16x8 v1 = *reinterpret_cast<const u16x8*>(&Hh[(size_t)p1.y * H_DIM + sl * 8]);
        u16x8 v2 = *reinterpret_cast<const u16x8*>(&Hh[(size_t)p2.y * H_DIM + sl * 8]);
        u16x8 v3 = *reinterpret_cast<const u16x8*>(&Hh[(size_t)p3.y * H_DIM + sl * 8]);
        float w0 = __uint_as_float(p0.x), w1 = __uint_as_float(p1.x);
        float w2 = __uint_as_float(p2.x), w3 = __uint_as_float(p3.x);
#pragma unroll
        for (int q = 0; q < 8; ++q) {
            a[q] = fmaf(w0, h2f(v0[q]), a[q]);
            a[q] = fmaf(w1, h2f(v1[q]), a[q]);
            a[q] = fmaf(w2, h2f(v2[q]), a[q]);
            a[q] = fmaf(w3, h2f(v3[q]), a[q]);
        }
    }
    for (; e < end; ++e) {
        uint2 p = csr_pk[e];
        float w = __uint_as_float(p.x);
        u16x8 v = *reinterpret_cast<const u16x8*>(&Hh[(size_t)p.y * H_DIM + sl * 8]);
#pragma unroll
        for (int q = 0; q < 8; ++q) a[q] = fmaf(w, h2f(v[q]), a[q]);
    }
    size_t so = (size_t)n * H_DIM + sl * 8;
    float e2 = 2.0f + eps[layer];
    u16x8 hh = *reinterpret_cast<const u16x8*>(&Hh[so]);
    u16x8 hl = *reinterpret_cast<const u16x8*>(&Hl[so]);
    u16x8 o;
#pragma unroll
    for (int q = 0; q < 8; ++q)
        o[q] = f2h(e2 * (h2f(hh[q]) + h2f(hl[q])) + a[q]);
    *reinterpret_cast<u16x8*>(&Ah[so]) = o;
}

// ---- weight transpose -> fp16: T[l][c][r] = f16(W[l][r][c]), coalesced -------
__global__ void k_wprep(const float* __restrict__ W, u16* __restrict__ T, int R, int C) {
    __shared__ float tile[64][65];
    int c0 = blockIdx.x * 64, r0 = blockIdx.y * 64;
    const float* Wl = W + (size_t)blockIdx.z * R * C;
    u16* Tl_ = T + (size_t)blockIdx.z * R * C;
    int t = threadIdx.x;
    int col = t & 63, qr = t >> 6;
#pragma unroll
    for (int i = 0; i < 16; ++i) {
        int row = i * 4 + qr;
        tile[row][col] = Wl[(size_t)(r0 + row) * C + c0 + col];
    }
    __syncthreads();
#pragma unroll
    for (int i = 0; i < 16; ++i) {
        int crow = i * 4 + qr;  // transposed row = original col
        Tl_[(size_t)(c0 + crow) * R + r0 + col] = f2h(tile[col][crow]);
    }
}

// ---- MFMA GEMM1: C1 = relu(A[MP,256] @ W1[256,512] + b), fp16 io -------------
// BK=64, 8-chunk XOR swizzle both-sides. Frag loads inside kk-loop keep live
// VGPR ~110 so __launch_bounds__(256,4) (4 blocks/CU) doesn't spill.
__global__ __launch_bounds__(256, 4) void k_mgemm1(
    const u16* __restrict__ Ah, const u16* __restrict__ Wt,
    const float* __restrict__ bias, u16* __restrict__ Ch) {
    __shared__ __align__(16) u16 sA[128 * 64];
    __shared__ __align__(16) u16 sB[128 * 64];
    const int t = threadIdx.x;
    const int wv = t >> 6, lane = t & 63;
    const int fr = lane & 15, kg = lane >> 4;
    const int m0 = blockIdx.x * 128, n0 = blockIdx.y * 128;
    const int wm = (wv >> 1) * 64, wn = (wv & 1) * 64;

    f32x4 acc[4][4];
#pragma unroll
    for (int i = 0; i < 4; ++i)
#pragma unroll
        for (int j = 0; j < 4; ++j) acc[i][j] = (f32x4){0.f, 0.f, 0.f, 0.f};

    for (int k0 = 0; k0 < 256; k0 += 64) {
#pragma unroll
        for (int i = 0; i < 4; ++i) {  // 1024 chunks each for A and B
            int ch = i * 256 + t;
            int r = ch >> 3, p = ch & 7;
            int ps = p ^ (r & 7);
            int lbase = (i * 256 + wv * 64) * 8;
            GLOAD16(Ah + (size_t)(m0 + r) * 256 + k0 + ps * 8, &sA[lbase]);
            GLOAD16(Wt + (size_t)(n0 + r) * 256 + k0 + ps * 8, &sB[lbase]);
        }
        __syncthreads();
#pragma unroll
        for (int kk = 0; kk < 2; ++kk) {
            f16x8 fa[4], fb[4];
#pragma unroll
            for (int mf = 0; mf < 4; ++mf) {
                int row = wm + mf * 16 + fr;
                int qs = (kk * 4 + kg) ^ (row & 7);
                fa[mf] = *(const f16x8*)&sA[row * 64 + qs * 8];
            }
#pragma unroll
            for (int nf = 0; nf < 4; ++nf) {
                int row = wn + nf * 16 + fr;
                int qs = (kk * 4 + kg) ^ (row & 7);
                fb[nf] = *(const f16x8*)&sB[row * 64 + qs * 8];
            }
#pragma unroll
            for (int mf = 0; mf < 4; ++mf)
#pragma unroll
                for (int nf = 0; nf < 4; ++nf)
                    acc[mf][nf] = __builtin_amdgcn_mfma_f32_16x16x32_f16(fa[mf], fb[nf], acc[mf][nf], 0, 0, 0);
        }
        __syncthreads();
    }
#pragma unroll
    for (int nf = 0; nf < 4; ++nf) {
        int col = n0 + wn + nf * 16 + fr;
        float bi = bias[col];
#pragma unroll
        for (int mf = 0; mf < 4; ++mf)
#pragma unroll
            for (int j = 0; j < 4; ++j) {
                int grow = m0 + wm + mf * 16 + kg * 4 + j;
                Ch[(size_t)grow * 512 + col] = f2h(relu_f(acc[mf][nf][j] + bi));
            }
    }
}

// -- MFMA GEMM2 + LN + relu + residual: hout = relu(LN(C1@W2+b2)) + hres -------
// LDS 42 KB -> 3 blocks/CU via __launch_bounds__(256,3); kk-split frag loads.
__global__ __launch_bounds__(256, 3) void k_mgemm2(
    const u16* __restrict__ Ah, const u16* __restrict__ Wt,
    const float* __restrict__ bias, const float* __restrict__ lg,
    const float* __restrict__ lbv,
    const u16* __restrict__ Rh, const u16* __restrict__ Rl,
    u16* __restrict__ Oh, u16* __restrict__ Ol) {
    __shared__ __align__(16) u16 sA[64 * 64];
    __shared__ __align__(16) u16 sB[256 * 64];
    __shared__ float lnS[64][4], lnS2[64][4];
    __shared__ float lnm[64], lnr[64];
    const int t = threadIdx.x;
    const int wv = t >> 6, lane = t & 63;
    const int fr = lane & 15, kg = lane >> 4;
    const int m0 = blockIdx.x * 64;

    f32x4 acc[4][4];
#pragma unroll
    for (int i = 0; i < 4; ++i)
#pragma unroll
        for (int j = 0; j < 4; ++j) acc[i][j] = (f32x4){0.f, 0.f, 0.f, 0.f};

    for (int k0 = 0; k0 < 512; k0 += 64) {
#pragma unroll
        for (int i = 0; i < 2; ++i) {  // sA: 512 chunks
            int ch = i * 256 + t;
            int r = ch >> 3, p = ch & 7;
            int ps = p ^ (r & 7);
            GLOAD16(Ah + (size_t)(m0 + r) * 512 + k0 + ps * 8, &sA[(i * 256 + wv * 64) * 8]);
        }
#pragma unroll
        for (int i = 0; i < 8; ++i) {  // sB: 2048 chunks
            int ch = i * 256 + t;
            int r = ch >> 3, p = ch & 7;
            int ps = p ^ (r & 7);
            GLOAD16(Wt + (size_t)r * 512 + k0 + ps * 8, &sB[(i * 256 + wv * 64) * 8]);
        }
        __syncthreads();
#pragma unroll
        for (int kk = 0; kk < 2; ++kk) {
            f16x8 fa[4], fb[4];
#pragma unroll
            for (int mf = 0; mf < 4; ++mf) {
                int row = mf * 16 + fr;
                int qs = (kk * 4 + kg) ^ (row & 7);
                fa[mf] = *(const f16x8*)&sA[row * 64 + qs * 8];
            }
#pragma unroll
            for (int nf = 0; nf < 4; ++nf) {
                int row = wv * 64 + nf * 16 + fr;
                int qs = (kk * 4 + kg) ^ (row & 7);
                fb[nf] = *(const f16x8*)&sB[row * 64 + qs * 8];
            }
#pragma unroll
            for (int mf = 0; mf < 4; ++mf)
#pragma unroll
                for (int nf = 0; nf < 4; ++nf)
                    acc[mf][nf] = __builtin_amdgcn_mfma_f32_16x16x32_f16(fa[mf], fb[nf], acc[mf][nf], 0, 0, 0);
        }
        __syncthreads();
    }
    float bcol[4];
#pragma unroll
    for (int nf = 0; nf < 4; ++nf) bcol[nf] = bias[wv * 64 + nf * 16 + fr];
#pragma unroll
    for (int mf = 0; mf < 4; ++mf)
#pragma unroll
        for (int nf = 0; nf < 4; ++nf)
#pragma unroll
            for (int j = 0; j < 4; ++j) acc[mf][nf][j] += bcol[nf];
#pragma unroll
    for (int mf = 0; mf < 4; ++mf)
#pragma unroll
        for (int j = 0; j < 4; ++j) {
            float s = acc[mf][0][j] + acc[mf][1][j] + acc[mf][2][j] + acc[mf][3][j];
            float s2 = acc[mf][0][j] * acc[mf][0][j] + acc[mf][1][j] * acc[mf][1][j] +
                       acc[mf][2][j] * acc[mf][2][j] + acc[mf][3][j] * acc[mf][3][j];
#pragma unroll
            for (int off = 1; off < 16; off <<= 1) {
                s += __shfl_xor(s, off);
                s2 += __shfl_xor(s2, off);
            }
            if (fr == 0) {
                int row = mf * 16 + kg * 4 + j;
                lnS[row][wv] = s;
                lnS2[row][wv] = s2;
            }
        }
    __syncthreads();
    if (t < 64) {
        float s = lnS[t][0] + lnS[t][1] + lnS[t][2] + lnS[t][3];
        float s2 = lnS2[t][0] + lnS2[t][1] + lnS2[t][2] + lnS2[t][3];
        float m = s * (1.f / 256.f);
        float var = s2 * (1.f / 256.f) - m * m;
        lnm[t] = m;
        lnr[t] = rsqrtf(var + LN_EPS);
    }
    __syncthreads();
    float gg[4], bb[4];
#pragma unroll
    for (int nf = 0; nf < 4; ++nf) {
        int col = wv * 64 + nf * 16 + fr;
        gg[nf] = lg[col];
        bb[nf] = lbv[col];
    }
#pragma unroll
    for (int mf = 0; mf < 4; ++mf)
#pragma unroll
        for (int j = 0; j < 4; ++j) {
            int row = mf * 16 + kg * 4 + j;
            int grow = m0 + row;
            float m = lnm[row], rs = lnr[row];
#pragma unroll
            for (int nf = 0; nf < 4; ++nf) {
                int col = wv * 64 + nf * 16 + fr;
                size_t o = (size_t)grow * 256 + col;
                float res = h2f(Rh[o]) + h2f(Rl[o]);
                float v = relu_f(gg[nf] * (acc[mf][nf][j] - m) * rs + bb[nf]) + res;
                u16 hh = f2h(v);
                Oh[o] = hh;
                Ol[o] = f2h(v - h2f(hh));
            }
        }
}

// -------- pooling (mean + max per graph), 4 col-chunks x 4-way rows -----------
__global__ void k_pool(const u16* __restrict__ Hh, const u16* __restrict__ Hl,
                       const int* __restrict__ gstart,
                       const int* __restrict__ gcnt, float* __restrict__ g) {
    int b = blockIdx.x;
    int col = blockIdx.y * 64 + (threadIdx.x & 63);
    int r = threadIdx.x >> 6;
    int st = gstart[b], cnt = gcnt[b];
    float s = 0.f, mx = -3.4e38f;
    for (int i = r; i < cnt; i += 4) {
        size_t o = (size_t)(st + i) * H_DIM + col;
        float v = h2f(Hh[o]) + h2f(Hl[o]);
        s += v;
        mx = fmaxf(mx, v);
    }
    __shared__ float ss[256], sm[256];
    ss[threadIdx.x] = s;
    sm[threadIdx.x] = mx;
    __syncthreads();
    if (r == 0) {
#pragma unroll
        for (int k = 1; k < 4; ++k) {
            s += ss[threadIdx.x + 64 * k];
            mx = fmaxf(mx, sm[threadIdx.x + 64 * k]);
        }
        float mean = cnt > 0 ? s / (float)cnt : 0.f;
        if (cnt == 0) mx = 0.f;
        g[b * 640 + col] = mean;
        g[b * 640 + 256 + col] = mx;
    }
}

// ---------------- gene projection --------------------------------------------
__global__ void k_gene(const float* __restrict__ gf, const float* __restrict__ Wg1,
                       const float* __restrict__ bg1, const float* __restrict__ lg,
                       const float* __restrict__ lb, const float* __restrict__ Wg2,
                       const float* __restrict__ bg2, float* __restrict__ g) {
    int b = blockIdx.x, t = threadIdx.x;
    __shared__ float xs[GF_DIM];
    __shared__ float sbuf[8];
    __shared__ float s1[H_DIM];
    if (t < GF_DIM) xs[t] = gf[b * GF_DIM + t];
    __syncthreads();
    float acc = bg1[t];
    for (int k = 0; k < GF_DIM; ++k) acc = fmaf(xs[k], Wg1[k * H_DIM + t], acc);
    float mean, rstd;
    ln_stats_256(acc, sbuf, mean, rstd);
    s1[t] = relu_f(lg[t] * (acc - mean) * rstd + lb[t]);
    __syncthreads();
    if (t < 128) {
        float a2 = bg2[t];
        for (int k = 0; k < H_DIM; ++k) a2 = fmaf(s1[k], Wg2[k * 128 + t], a2);
        g[b * 640 + 512 + t] = relu_f(a2);
    }
}

// ---------------- classifier --------------------------------------------------
__global__ void k_cls(const float* __restrict__ g, const float* __restrict__ Wc1,
                      const float* __restrict__ bc1, const float* __restrict__ Wc2,
                      const float* __restrict__ bc2, const float* __restrict__ Wc3,
                      const float* __restrict__ bc3, float* __restrict__ out) {
    int b = blockIdx.x, t = threadIdx.x;
    __shared__ float gg[640];
    __shared__ float s1[256];
    __shared__ float s2[128];
    gg[t] = g[b * 640 + t];
    gg[t + 256] = g[b * 640 + 256 + t];
    if (t < 128) gg[t + 512] = g[b * 640 + 512 + t];
    __syncthreads();
    float a = bc1[t];
    for (int k = 0; k < 640; ++k) a = fmaf(gg[k], Wc1[k * 256 + t], a);
    s1[t] = relu_f(a);
    __syncthreads();
    if (t < 128) {
        float a2 = bc2[t];
        for (int k = 0; k < 256; ++k) a2 = fmaf(s1[k], Wc2[k * 128 + t], a2);
        s2[t] = relu_f(a2);
    }
    __syncthreads();
    if (t < 2) {
        float a3 = bc3[t];
        for (int k = 0; k < 128; ++k) a3 = fmaf(s2[k], Wc3[k * 2 + t], a3);
        out[b * 2 + t] = a3;
    }
}

extern "C" void kernel_launch(void* const* d_in, const int* in_sizes, int n_in,
                              void* d_out, int out_size, void* d_ws, size_t ws_size,
                              hipStream_t stream) {
    const float* x = (const float*)d_in[0];
    const int* ei = (const int*)d_in[1];
    const float* ew = (const float*)d_in[2];
    const int* batch = (const int*)d_in[3];
    const float* gf = (const float*)d_in[4];
    const float* W_in = (const float*)d_in[5];
    const float* b_in = (const float*)d_in[6];
    const float* ln_in_g = (const float*)d_in[7];
    const float* ln_in_b = (const float*)d_in[8];
    const float* eps = (const float*)d_in[9];
    const float* W1 = (const float*)d_in[10];
    const float* b1 = (const float*)d_in[11];
    const float* W2 = (const float*)d_in[12];
    const float* b2 = (const float*)d_in[13];
    const float* ln_g = (const float*)d_in[14];
    const float* ln_b = (const float*)d_in[15];
    const float* Wg1 = (const float*)d_in[16];
    const float* bg1 = (const float*)d_in[17];
    const float* lng_g = (const float*)d_in[18];
    const float* lng_b = (const float*)d_in[19];
    const float* Wg2 = (const float*)d_in[20];
    const float* bg2 = (const float*)d_in[21];
    const float* Wc1 = (const float*)d_in[22];
    const float* bc1 = (const float*)d_in[23];
    const float* Wc2 = (const float*)d_in[24];
    const float* bc2 = (const float*)d_in[25];
    const float* Wc3 = (const float*)d_in[26];
    const float* bc3 = (const float*)d_in[27];
    float* out = (float*)d_out;

    char* ws = (char*)d_ws;
    size_t off = 0;
    auto alloc = [&](size_t bytes) -> char* {
        char* p = ws + off;
        off += (bytes + 255) & ~(size_t)255;
        return p;
    };
    u16* Hh0 = (u16*)alloc((size_t)MP * H_DIM * 2);
    u16* Hl0 = (u16*)alloc((size_t)MP * H_DIM * 2);
    u16* Hh1 = (u16*)alloc((size_t)MP * H_DIM * 2);
    u16* Hl1 = (u16*)alloc((size_t)MP * H_DIM * 2);
    u16* Ah = (u16*)alloc((size_t)MP * H_DIM * 2);
    u16* C1h = (u16*)alloc((size_t)MP * H2_DIM * 2);
    u16* W1T = (u16*)alloc((size_t)4 * H2_DIM * H_DIM * 2);
    u16* W2T = (u16*)alloc((size_t)4 * H_DIM * H2_DIM * 2);
    int* deg = (int*)alloc(N_NODES * 4);
    int* cursor = (int*)alloc(N_NODES * 4);
    int* row_start = (int*)alloc((N_NODES + 1) * 4);
    int* bsum = (int*)alloc(256 * 4);
    int* gcnt = (int*)alloc(N_B * 4);
    int* gstart = (int*)alloc(N_B * 4);
    uint2* csr_pk = (uint2*)alloc((size_t)N_EDGES * 8);
    float* gbuf = (float*)alloc(N_B * 640 * 4);
    (void)ws_size; (void)in_sizes; (void)n_in; (void)out_size;

    // zero deg + cursor — span computed from pointers so padding is covered
    hipMemsetAsync(deg, 0, (size_t)((char*)row_start - (char*)deg), stream);

    // weight transpose -> fp16 (coalesced LDS-tile transpose)
    k_wprep<<<dim3(H2_DIM / 64, H_DIM / 64, 4), 256, 0, stream>>>(W1, W1T, H_DIM, H2_DIM);
    k_wprep<<<dim3(H_DIM / 64, H2_DIM / 64, 4), 256, 0, stream>>>(W2, W2T, H2_DIM, H_DIM);

    k_input_proj<<<N_NODES, 256, 0, stream>>>(x, W_in, b_in, ln_in_g, ln_in_b, Hh0, Hl0);
    k_hist<<<N_EDGES / 256, 256, 0, stream>>>(ei, deg);
    k_scan1<<<SCAN_NBLK, 256, 0, stream>>>(deg, row_start, bsum);
    k_scan2<<<1, 256, 0, stream>>>(bsum);
    k_scan3<<<SCAN_NBLK, 256, 0, stream>>>(row_start, bsum);
    k_scatter<<<N_EDGES / 256, 256, 0, stream>>>(ei, ew, row_start, cursor, csr_pk);
    k_gbounds<<<1, N_B, 0, stream>>>(batch, gstart, gcnt);

    u16* hch = Hh0; u16* hcl = Hl0;
    u16* hnh = Hh1; u16* hnl = Hl1;
    for (int l = 0; l < 4; ++l) {
        k_agg<<<N_NODES / 8, 256, 0, stream>>>(hch, hcl, row_start, csr_pk, eps, l, Ah);
        k_mgemm1<<<dim3(MP / 128, 4), 256, 0, stream>>>(
            Ah, W1T + (size_t)l * H2_DIM * H_DIM,
            b1 + (size_t)l * H2_DIM, C1h);
        k_mgemm2<<<MP / 64, 256, 0, stream>>>(
            C1h, W2T + (size_t)l * H_DIM * H2_DIM,
            b2 + (size_t)l * H_DIM, ln_g + (size_t)l * H_DIM, ln_b + (size_t)l * H_DIM,
            hch, hcl, hnh, hnl);
        u16* th = hch; hch = hnh; hnh = th;
        u16* tl = hcl; hcl = hnl; hnl = tl;
    }

    k_pool<<<dim3(N_B, 4), 256, 0, stream>>>(hch, hcl, gstart, gcnt, gbuf);
    k_gene<<<N_B, 256, 0, stream>>>(gf, Wg1, bg1, lng_g, lng_b, Wg2, bg2, gbuf);
    k_cls<<<N_B, 256, 0, stream>>>(gbuf, Wc1, bc1, Wc2, bc2, Wc3, bc3, out);
}

// Round 14
// 756.470 us; speedup vs baseline: 1.0619x; 1.0619x over previous
//
#include <hip/hip_runtime.h>
#include <hip/hip_bf16.h>

#define N_NODES 50000
#define MP 50048            // padded row count (multiple of 128)
#define N_EDGES 800000
#define N_B 128
#define H_DIM 256
#define H2_DIM 512
#define FIN_DIM 8
#define GF_DIM 85
#define LN_EPS 1e-5f
#define SCAN_NBLK 196       // ceil(50000/256)

typedef unsigned short u16;
typedef unsigned int u32;
typedef _Float16 f16;
typedef __attribute__((ext_vector_type(8))) _Float16 f16x8;
typedef __attribute__((ext_vector_type(8))) unsigned short u16x8;
typedef __attribute__((ext_vector_type(4))) float f32x4;

__device__ inline float relu_f(float x) { return x > 0.f ? x : 0.f; }

__device__ inline float h2f(u16 b) { f16 h; __builtin_memcpy(&h, &b, 2); return (float)h; }
__device__ inline u16 f2h(float x) { f16 h = (f16)x; u16 b; __builtin_memcpy(&b, &h, 2); return b; }

#define GLOAD16(gp, lp) __builtin_amdgcn_global_load_lds( \
    (const __attribute__((address_space(1))) void*)(gp),  \
    (__attribute__((address_space(3))) void*)(lp), 16, 0, 0)

// LayerNorm stats across a 256-thread block (one value per thread)
__device__ inline void ln_stats_256(float v, float* sbuf, float& mean, float& rstd) {
    float s = v, s2 = v * v;
#pragma unroll
    for (int off = 32; off > 0; off >>= 1) {
        s += __shfl_down(s, off);
        s2 += __shfl_down(s2, off);
    }
    int t = threadIdx.x;
    if ((t & 63) == 0) { sbuf[t >> 6] = s; sbuf[4 + (t >> 6)] = s2; }
    __syncthreads();
    float ts = sbuf[0] + sbuf[1] + sbuf[2] + sbuf[3];
    float ts2 = sbuf[4] + sbuf[5] + sbuf[6] + sbuf[7];
    mean = ts * (1.f / H_DIM);
    float var = ts2 * (1.f / H_DIM) - mean * mean;
    rstd = rsqrtf(var + LN_EPS);
}

// --- input projection: h = relu(LN(x @ W_in + b_in)), split-fp16 out ---------
__global__ void k_input_proj(const float* __restrict__ x, const float* __restrict__ Wi,
                             const float* __restrict__ bi, const float* __restrict__ g,
                             const float* __restrict__ bb,
                             u16* __restrict__ Hh, u16* __restrict__ Hl) {
    int n = blockIdx.x, t = threadIdx.x;
    __shared__ float xs[FIN_DIM];
    __shared__ float sbuf[8];
    if (t < FIN_DIM) xs[t] = x[n * FIN_DIM + t];
    __syncthreads();
    float acc = bi[t];
#pragma unroll
    for (int k = 0; k < FIN_DIM; ++k) acc = fmaf(xs[k], Wi[k * H_DIM + t], acc);
    float mean, rstd;
    ln_stats_256(acc, sbuf, mean, rstd);
    float v = relu_f(g[t] * (acc - mean) * rstd + bb[t]);
    u16 hh = f2h(v);
    size_t o = (size_t)n * H_DIM + t;
    Hh[o] = hh;
    Hl[o] = f2h(v - h2f(hh));
}

// ---------------- CSR build ---------------------------------------------------
__global__ void k_hist(const int* __restrict__ ei, int* __restrict__ deg) {
    int e = blockIdx.x * 256 + threadIdx.x;
    atomicAdd(&deg[ei[N_EDGES + e]], 1);
}

// 3-stage parallel exclusive scan of deg -> row_start
__global__ void k_scan1(const int* __restrict__ deg, int* __restrict__ row_start,
                        int* __restrict__ bsum) {
    __shared__ int s[256];
    int t = threadIdx.x, i = blockIdx.x * 256 + t;
    int v = (i < N_NODES) ? deg[i] : 0;
    s[t] = v;
    __syncthreads();
    for (int off = 1; off < 256; off <<= 1) {
        int x = (t >= off) ? s[t - off] : 0;
        __syncthreads();
        s[t] += x;
        __syncthreads();
    }
    if (i < N_NODES) row_start[i] = s[t] - v;  // exclusive within block
    if (t == 255) bsum[blockIdx.x] = s[255];
}

__global__ void k_scan2(int* __restrict__ bsum) {
    __shared__ int s[256];
    int t = threadIdx.x;
    int v = (t < SCAN_NBLK) ? bsum[t] : 0;
    s[t] = v;
    __syncthreads();
    for (int off = 1; off < 256; off <<= 1) {
        int x = (t >= off) ? s[t - off] : 0;
        __syncthreads();
        s[t] += x;
        __syncthreads();
    }
    if (t < SCAN_NBLK) bsum[t] = s[t] - v;  // exclusive block offsets
}

__global__ void k_scan3(int* __restrict__ row_start, const int* __restrict__ bsum) {
    int t = threadIdx.x, i = blockIdx.x * 256 + t;
    if (i < N_NODES) row_start[i] += bsum[blockIdx.x];
    if (i == 0) row_start[N_NODES] = N_EDGES;
}

// packed CSR payload: one 8B struct {w_bits, src} -> ONE random store per edge
__global__ void k_scatter(const int* __restrict__ ei, const float* __restrict__ ew,
                          const int* __restrict__ row_start, int* __restrict__ cursor,
                          uint2* __restrict__ csr_pk) {
    int e = blockIdx.x * 256 + threadIdx.x;
    int d = ei[N_EDGES + e];
    int p = atomicAdd(&cursor[d], 1);
    int i = row_start[d] + p;
    uint2 pk;
    pk.x = __float_as_uint(ew[e]);
    pk.y = (u32)ei[e];
    csr_pk[i] = pk;
}

// batch is sorted: graph b occupies [gstart[b], gstart[b+1])  — binary search
__global__ void k_gbounds(const int* __restrict__ batch, int* __restrict__ gstart,
                          int* __restrict__ gcnt) {
    __shared__ int s[N_B + 1];
    int b = threadIdx.x;  // 0..127
    int lo = 0, hi = N_NODES;
    while (lo < hi) {
        int mid = (lo + hi) >> 1;
        if (batch[mid] < b) lo = mid + 1; else hi = mid;
    }
    s[b] = lo;
    if (b == 0) s[N_B] = N_NODES;
    __syncthreads();
    gstart[b] = s[b];
    gcnt[b] = s[b + 1] - s[b];
}

// ---- GIN aggregation: A = fp16( (2+eps)*h + sum_in w*Hh[src] ) ---------------
// half-wave per node (avg degree 16); 8-deep unrolled gather prefetch.
__global__ void k_agg(const u16* __restrict__ Hh, const u16* __restrict__ Hl,
                      const int* __restrict__ row_start,
                      const uint2* __restrict__ csr_pk,
                      const float* __restrict__ eps, int layer,
                      u16* __restrict__ Ah) {
    const int t = threadIdx.x;
    const int n = blockIdx.x * 8 + (t >> 5);
    const int sl = t & 31;
    int start = row_start[n], end = row_start[n + 1];
    float a[8];
#pragma unroll
    for (int q = 0; q < 8; ++q) a[q] = 0.f;
    int e = start;
    for (; e + 7 < end; e += 8) {
        uint2 pk[8];
        u16x8 vv[8];
#pragma unroll
        for (int d = 0; d < 8; ++d) pk[d] = csr_pk[e + d];
#pragma unroll
        for (int d = 0; d < 8; ++d)
            vv[d] = *reinterpret_cast<const u16x8*>(&Hh[(size_t)pk[d].y * H_DIM + sl * 8]);
#pragma unroll
        for (int d = 0; d < 8; ++d) {
            float w = __uint_as_float(pk[d].x);
#pragma unroll
            for (int q = 0; q < 8; ++q) a[q] = fmaf(w, h2f(vv[d][q]), a[q]);
        }
    }
    for (; e + 3 < end; e += 4) {
        uint2 p0 = csr_pk[e], p1 = csr_pk[e + 1], p2 = csr_pk[e + 2], p3 = csr_pk[e + 3];
        u16x8 v0 = *reinterpret_cast<const u16x8*>(&Hh[(size_t)p0.y * H_DIM + sl * 8]);
        u16x8 v1 = *reinterpret_cast<const u16x8*>(&Hh[(size_t)p1.y * H_DIM + sl * 8]);
        u16x8 v2 = *reinterpret_cast<const u16x8*>(&Hh[(size_t)p2.y * H_DIM + sl * 8]);
        u16x8 v3 = *reinterpret_cast<const u16x8*>(&Hh[(size_t)p3.y * H_DIM + sl * 8]);
        float w0 = __uint_as_float(p0.x), w1 = __uint_as_float(p1.x);
        float w2 = __uint_as_float(p2.x), w3 = __uint_as_float(p3.x);
#pragma unroll
        for (int q = 0; q < 8; ++q) {
            a[q] = fmaf(w0, h2f(v0[q]), a[q]);
            a[q] = fmaf(w1, h2f(v1[q]), a[q]);
            a[q] = fmaf(w2, h2f(v2[q]), a[q]);
            a[q] = fmaf(w3, h2f(v3[q]), a[q]);
        }
    }
    for (; e < end; ++e) {
        uint2 p = csr_pk[e];
        float w = __uint_as_float(p.x);
        u16x8 v = *reinterpret_cast<const u16x8*>(&Hh[(size_t)p.y * H_DIM + sl * 8]);
#pragma unroll
        for (int q = 0; q < 8; ++q) a[q] = fmaf(w, h2f(v[q]), a[q]);
    }
    size_t so = (size_t)n * H_DIM + sl * 8;
    float e2 = 2.0f + eps[layer];
    u16x8 hh = *reinterpret_cast<const u16x8*>(&Hh[so]);
    u16x8 hl = *reinterpret_cast<const u16x8*>(&Hl[so]);
    u16x8 o;
#pragma unroll
    for (int q = 0; q < 8; ++q)
        o[q] = f2h(e2 * (h2f(hh[q]) + h2f(hl[q])) + a[q]);
    *reinterpret_cast<u16x8*>(&Ah[so]) = o;
}

// ---- weight transpose -> fp16: T[l][c][r] = f16(W[l][r][c]), coalesced -------
__global__ void k_wprep(const float* __restrict__ W, u16* __restrict__ T, int R, int C) {
    __shared__ float tile[64][65];
    int c0 = blockIdx.x * 64, r0 = blockIdx.y * 64;
    const float* Wl = W + (size_t)blockIdx.z * R * C;
    u16* Tl_ = T + (size_t)blockIdx.z * R * C;
    int t = threadIdx.x;
    int col = t & 63, qr = t >> 6;
#pragma unroll
    for (int i = 0; i < 16; ++i) {
        int row = i * 4 + qr;
        tile[row][col] = Wl[(size_t)(r0 + row) * C + c0 + col];
    }
    __syncthreads();
#pragma unroll
    for (int i = 0; i < 16; ++i) {
        int crow = i * 4 + qr;  // transposed row = original col
        Tl_[(size_t)(c0 + crow) * R + r0 + col] = f2h(tile[col][crow]);
    }
}

// ---- MFMA GEMM1: C1 = relu(A[MP,256] @ W1[256,512] + b), fp16 io -------------
// BK=64: LDS rows are 128B (all 32 banks) -> 8-chunk XOR swizzle (chunk ^= row&7)
// applied on the gload SOURCE and the fragment read (both-sides involution).
__global__ __launch_bounds__(256, 2) void k_mgemm1(
    const u16* __restrict__ Ah, const u16* __restrict__ Wt,
    const float* __restrict__ bias, u16* __restrict__ Ch) {
    __shared__ __align__(16) u16 sA[128 * 64];
    __shared__ __align__(16) u16 sB[128 * 64];
    const int t = threadIdx.x;
    const int wv = t >> 6, lane = t & 63;
    const int fr = lane & 15, kg = lane >> 4;
    const int m0 = blockIdx.x * 128, n0 = blockIdx.y * 128;
    const int wm = (wv >> 1) * 64, wn = (wv & 1) * 64;

    f32x4 acc[4][4];
#pragma unroll
    for (int i = 0; i < 4; ++i)
#pragma unroll
        for (int j = 0; j < 4; ++j) acc[i][j] = (f32x4){0.f, 0.f, 0.f, 0.f};

    for (int k0 = 0; k0 < 256; k0 += 64) {
#pragma unroll
        for (int i = 0; i < 4; ++i) {  // 1024 chunks each for A and B
            int ch = i * 256 + t;
            int r = ch >> 3, p = ch & 7;
            int ps = p ^ (r & 7);
            int lbase = (i * 256 + wv * 64) * 8;
            GLOAD16(Ah + (size_t)(m0 + r) * 256 + k0 + ps * 8, &sA[lbase]);
            GLOAD16(Wt + (size_t)(n0 + r) * 256 + k0 + ps * 8, &sB[lbase]);
        }
        __syncthreads();
        f16x8 fa[4][2], fb[4][2];
#pragma unroll
        for (int mf = 0; mf < 4; ++mf) {
            int row = wm + mf * 16 + fr;
#pragma unroll
            for (int kk = 0; kk < 2; ++kk) {
                int qs = (kk * 4 + kg) ^ (row & 7);
                fa[mf][kk] = *(const f16x8*)&sA[row * 64 + qs * 8];
            }
        }
#pragma unroll
        for (int nf = 0; nf < 4; ++nf) {
            int row = wn + nf * 16 + fr;
#pragma unroll
            for (int kk = 0; kk < 2; ++kk) {
                int qs = (kk * 4 + kg) ^ (row & 7);
                fb[nf][kk] = *(const f16x8*)&sB[row * 64 + qs * 8];
            }
        }
#pragma unroll
        for (int kk = 0; kk < 2; ++kk)
#pragma unroll
            for (int mf = 0; mf < 4; ++mf)
#pragma unroll
                for (int nf = 0; nf < 4; ++nf)
                    acc[mf][nf] = __builtin_amdgcn_mfma_f32_16x16x32_f16(fa[mf][kk], fb[nf][kk], acc[mf][nf], 0, 0, 0);
        __syncthreads();
    }
#pragma unroll
    for (int nf = 0; nf < 4; ++nf) {
        int col = n0 + wn + nf * 16 + fr;
        float bi = bias[col];
#pragma unroll
        for (int mf = 0; mf < 4; ++mf)
#pragma unroll
            for (int j = 0; j < 4; ++j) {
                int grow = m0 + wm + mf * 16 + kg * 4 + j;
                Ch[(size_t)grow * 512 + col] = f2h(relu_f(acc[mf][nf][j] + bi));
            }
    }
}

// -- MFMA GEMM2 + LN + relu + residual: hout = relu(LN(C1@W2+b2)) + hres -------
__global__ __launch_bounds__(256, 2) void k_mgemm2(
    const u16* __restrict__ Ah, const u16* __restrict__ Wt,
    const float* __restrict__ bias, const float* __restrict__ lg,
    const float* __restrict__ lbv,
    const u16* __restrict__ Rh, const u16* __restrict__ Rl,
    u16* __restrict__ Oh, u16* __restrict__ Ol) {
    __shared__ __align__(16) u16 sA[64 * 64];
    __shared__ __align__(16) u16 sB[256 * 64];
    __shared__ float lnS[64][4], lnS2[64][4];
    __shared__ float lnm[64], lnr[64];
    const int t = threadIdx.x;
    const int wv = t >> 6, lane = t & 63;
    const int fr = lane & 15, kg = lane >> 4;
    const int m0 = blockIdx.x * 64;

    f32x4 acc[4][4];
#pragma unroll
    for (int i = 0; i < 4; ++i)
#pragma unroll
        for (int j = 0; j < 4; ++j) acc[i][j] = (f32x4){0.f, 0.f, 0.f, 0.f};

    for (int k0 = 0; k0 < 512; k0 += 64) {
#pragma unroll
        for (int i = 0; i < 2; ++i) {  // sA: 512 chunks
            int ch = i * 256 + t;
            int r = ch >> 3, p = ch & 7;
            int ps = p ^ (r & 7);
            GLOAD16(Ah + (size_t)(m0 + r) * 512 + k0 + ps * 8, &sA[(i * 256 + wv * 64) * 8]);
        }
#pragma unroll
        for (int i = 0; i < 8; ++i) {  // sB: 2048 chunks
            int ch = i * 256 + t;
            int r = ch >> 3, p = ch & 7;
            int ps = p ^ (r & 7);
            GLOAD16(Wt + (size_t)r * 512 + k0 + ps * 8, &sB[(i * 256 + wv * 64) * 8]);
        }
        __syncthreads();
        f16x8 fa[4][2], fb[4][2];
#pragma unroll
        for (int mf = 0; mf < 4; ++mf) {
            int row = mf * 16 + fr;
#pragma unroll
            for (int kk = 0; kk < 2; ++kk) {
                int qs = (kk * 4 + kg) ^ (row & 7);
                fa[mf][kk] = *(const f16x8*)&sA[row * 64 + qs * 8];
            }
        }
#pragma unroll
        for (int nf = 0; nf < 4; ++nf) {
            int row = wv * 64 + nf * 16 + fr;
#pragma unroll
            for (int kk = 0; kk < 2; ++kk) {
                int qs = (kk * 4 + kg) ^ (row & 7);
                fb[nf][kk] = *(const f16x8*)&sB[row * 64 + qs * 8];
            }
        }
#pragma unroll
        for (int kk = 0; kk < 2; ++kk)
#pragma unroll
            for (int mf = 0; mf < 4; ++mf)
#pragma unroll
                for (int nf = 0; nf < 4; ++nf)
                    acc[mf][nf] = __builtin_amdgcn_mfma_f32_16x16x32_f16(fa[mf][kk], fb[nf][kk], acc[mf][nf], 0, 0, 0);
        __syncthreads();
    }
    float bcol[4];
#pragma unroll
    for (int nf = 0; nf < 4; ++nf) bcol[nf] = bias[wv * 64 + nf * 16 + fr];
#pragma unroll
    for (int mf = 0; mf < 4; ++mf)
#pragma unroll
        for (int nf = 0; nf < 4; ++nf)
#pragma unroll
            for (int j = 0; j < 4; ++j) acc[mf][nf][j] += bcol[nf];
#pragma unroll
    for (int mf = 0; mf < 4; ++mf)
#pragma unroll
        for (int j = 0; j < 4; ++j) {
            float s = acc[mf][0][j] + acc[mf][1][j] + acc[mf][2][j] + acc[mf][3][j];
            float s2 = acc[mf][0][j] * acc[mf][0][j] + acc[mf][1][j] * acc[mf][1][j] +
                       acc[mf][2][j] * acc[mf][2][j] + acc[mf][3][j] * acc[mf][3][j];
#pragma unroll
            for (int off = 1; off < 16; off <<= 1) {
                s += __shfl_xor(s, off);
                s2 += __shfl_xor(s2, off);
            }
            if (fr == 0) {
                int row = mf * 16 + kg * 4 + j;
                lnS[row][wv] = s;
                lnS2[row][wv] = s2;
            }
        }
    __syncthreads();
    if (t < 64) {
        float s = lnS[t][0] + lnS[t][1] + lnS[t][2] + lnS[t][3];
        float s2 = lnS2[t][0] + lnS2[t][1] + lnS2[t][2] + lnS2[t][3];
        float m = s * (1.f / 256.f);
        float var = s2 * (1.f / 256.f) - m * m;
        lnm[t] = m;
        lnr[t] = rsqrtf(var + LN_EPS);
    }
    __syncthreads();
    float gg[4], bb[4];
#pragma unroll
    for (int nf = 0; nf < 4; ++nf) {
        int col = wv * 64 + nf * 16 + fr;
        gg[nf] = lg[col];
        bb[nf] = lbv[col];
    }
#pragma unroll
    for (int mf = 0; mf < 4; ++mf)
#pragma unroll
        for (int j = 0; j < 4; ++j) {
            int row = mf * 16 + kg * 4 + j;
            int grow = m0 + row;
            float m = lnm[row], rs = lnr[row];
#pragma unroll
            for (int nf = 0; nf < 4; ++nf) {
                int col = wv * 64 + nf * 16 + fr;
                size_t o = (size_t)grow * 256 + col;
                float res = h2f(Rh[o]) + h2f(Rl[o]);
                float v = relu_f(gg[nf] * (acc[mf][nf][j] - m) * rs + bb[nf]) + res;
                u16 hh = f2h(v);
                Oh[o] = hh;
                Ol[o] = f2h(v - h2f(hh));
            }
        }
}

// -------- pooling (mean + max per graph), 4 col-chunks x 4-way rows -----------
__global__ void k_pool(const u16* __restrict__ Hh, const u16* __restrict__ Hl,
                       const int* __restrict__ gstart,
                       const int* __restrict__ gcnt, float* __restrict__ g) {
    int b = blockIdx.x;
    int col = blockIdx.y * 64 + (threadIdx.x & 63);
    int r = threadIdx.x >> 6;
    int st = gstart[b], cnt = gcnt[b];
    float s = 0.f, mx = -3.4e38f;
    for (int i = r; i < cnt; i += 4) {
        size_t o = (size_t)(st + i) * H_DIM + col;
        float v = h2f(Hh[o]) + h2f(Hl[o]);
        s += v;
        mx = fmaxf(mx, v);
    }
    __shared__ float ss[256], sm[256];
    ss[threadIdx.x] = s;
    sm[threadIdx.x] = mx;
    __syncthreads();
    if (r == 0) {
#pragma unroll
        for (int k = 1; k < 4; ++k) {
            s += ss[threadIdx.x + 64 * k];
            mx = fmaxf(mx, sm[threadIdx.x + 64 * k]);
        }
        float mean = cnt > 0 ? s / (float)cnt : 0.f;
        if (cnt == 0) mx = 0.f;
        g[b * 640 + col] = mean;
        g[b * 640 + 256 + col] = mx;
    }
}

// ---------------- gene projection --------------------------------------------
__global__ void k_gene(const float* __restrict__ gf, const float* __restrict__ Wg1,
                       const float* __restrict__ bg1, const float* __restrict__ lg,
                       const float* __restrict__ lb, const float* __restrict__ Wg2,
                       const float* __restrict__ bg2, float* __restrict__ g) {
    int b = blockIdx.x, t = threadIdx.x;
    __shared__ float xs[GF_DIM];
    __shared__ float sbuf[8];
    __shared__ float s1[H_DIM];
    if (t < GF_DIM) xs[t] = gf[b * GF_DIM + t];
    __syncthreads();
    float acc = bg1[t];
    for (int k = 0; k < GF_DIM; ++k) acc = fmaf(xs[k], Wg1[k * H_DIM + t], acc);
    float mean, rstd;
    ln_stats_256(acc, sbuf, mean, rstd);
    s1[t] = relu_f(lg[t] * (acc - mean) * rstd + lb[t]);
    __syncthreads();
    if (t < 128) {
        float a2 = bg2[t];
        for (int k = 0; k < H_DIM; ++k) a2 = fmaf(s1[k], Wg2[k * 128 + t], a2);
        g[b * 640 + 512 + t] = relu_f(a2);
    }
}

// ---------------- classifier --------------------------------------------------
__global__ void k_cls(const float* __restrict__ g, const float* __restrict__ Wc1,
                      const float* __restrict__ bc1, const float* __restrict__ Wc2,
                      const float* __restrict__ bc2, const float* __restrict__ Wc3,
                      const float* __restrict__ bc3, float* __restrict__ out) {
    int b = blockIdx.x, t = threadIdx.x;
    __shared__ float gg[640];
    __shared__ float s1[256];
    __shared__ float s2[128];
    gg[t] = g[b * 640 + t];
    gg[t + 256] = g[b * 640 + 256 + t];
    if (t < 128) gg[t + 512] = g[b * 640 + 512 + t];
    __syncthreads();
    float a = bc1[t];
    for (int k = 0; k < 640; ++k) a = fmaf(gg[k], Wc1[k * 256 + t], a);
    s1[t] = relu_f(a);
    __syncthreads();
    if (t < 128) {
        float a2 = bc2[t];
        for (int k = 0; k < 256; ++k) a2 = fmaf(s1[k], Wc2[k * 128 + t], a2);
        s2[t] = relu_f(a2);
    }
    __syncthreads();
    if (t < 2) {
        float a3 = bc3[t];
        for (int k = 0; k < 128; ++k) a3 = fmaf(s2[k], Wc3[k * 2 + t], a3);
        out[b * 2 + t] = a3;
    }
}

extern "C" void kernel_launch(void* const* d_in, const int* in_sizes, int n_in,
                              void* d_out, int out_size, void* d_ws, size_t ws_size,
                              hipStream_t stream) {
    const float* x = (const float*)d_in[0];
    const int* ei = (const int*)d_in[1];
    const float* ew = (const float*)d_in[2];
    const int* batch = (const int*)d_in[3];
    const float* gf = (const float*)d_in[4];
    const float* W_in = (const float*)d_in[5];
    const float* b_in = (const float*)d_in[6];
    const float* ln_in_g = (const float*)d_in[7];
    const float* ln_in_b = (const float*)d_in[8];
    const float* eps = (const float*)d_in[9];
    const float* W1 = (const float*)d_in[10];
    const float* b1 = (const float*)d_in[11];
    const float* W2 = (const float*)d_in[12];
    const float* b2 = (const float*)d_in[13];
    const float* ln_g = (const float*)d_in[14];
    const float* ln_b = (const float*)d_in[15];
    const float* Wg1 = (const float*)d_in[16];
    const float* bg1 = (const float*)d_in[17];
    const float* lng_g = (const float*)d_in[18];
    const float* lng_b = (const float*)d_in[19];
    const float* Wg2 = (const float*)d_in[20];
    const float* bg2 = (const float*)d_in[21];
    const float* Wc1 = (const float*)d_in[22];
    const float* bc1 = (const float*)d_in[23];
    const float* Wc2 = (const float*)d_in[24];
    const float* bc2 = (const float*)d_in[25];
    const float* Wc3 = (const float*)d_in[26];
    const float* bc3 = (const float*)d_in[27];
    float* out = (float*)d_out;

    char* ws = (char*)d_ws;
    size_t off = 0;
    auto alloc = [&](size_t bytes) -> char* {
        char* p = ws + off;
        off += (bytes + 255) & ~(size_t)255;
        return p;
    };
    u16* Hh0 = (u16*)alloc((size_t)MP * H_DIM * 2);
    u16* Hl0 = (u16*)alloc((size_t)MP * H_DIM * 2);
    u16* Hh1 = (u16*)alloc((size_t)MP * H_DIM * 2);
    u16* Hl1 = (u16*)alloc((size_t)MP * H_DIM * 2);
    u16* Ah = (u16*)alloc((size_t)MP * H_DIM * 2);
    u16* C1h = (u16*)alloc((size_t)MP * H2_DIM * 2);
    u16* W1T = (u16*)alloc((size_t)4 * H2_DIM * H_DIM * 2);
    u16* W2T = (u16*)alloc((size_t)4 * H_DIM * H2_DIM * 2);
    int* deg = (int*)alloc(N_NODES * 4);
    int* cursor = (int*)alloc(N_NODES * 4);
    int* row_start = (int*)alloc((N_NODES + 1) * 4);
    int* bsum = (int*)alloc(256 * 4);
    int* gcnt = (int*)alloc(N_B * 4);
    int* gstart = (int*)alloc(N_B * 4);
    uint2* csr_pk = (uint2*)alloc((size_t)N_EDGES * 8);
    float* gbuf = (float*)alloc(N_B * 640 * 4);
    (void)ws_size; (void)in_sizes; (void)n_in; (void)out_size;

    // zero deg + cursor — span computed from pointers so padding is covered
    hipMemsetAsync(deg, 0, (size_t)((char*)row_start - (char*)deg), stream);

    // weight transpose -> fp16 (coalesced LDS-tile transpose)
    k_wprep<<<dim3(H2_DIM / 64, H_DIM / 64, 4), 256, 0, stream>>>(W1, W1T, H_DIM, H2_DIM);
    k_wprep<<<dim3(H_DIM / 64, H2_DIM / 64, 4), 256, 0, stream>>>(W2, W2T, H2_DIM, H_DIM);

    k_input_proj<<<N_NODES, 256, 0, stream>>>(x, W_in, b_in, ln_in_g, ln_in_b, Hh0, Hl0);
    k_hist<<<N_EDGES / 256, 256, 0, stream>>>(ei, deg);
    k_scan1<<<SCAN_NBLK, 256, 0, stream>>>(deg, row_start, bsum);
    k_scan2<<<1, 256, 0, stream>>>(bsum);
    k_scan3<<<SCAN_NBLK, 256, 0, stream>>>(row_start, bsum);
    k_scatter<<<N_EDGES / 256, 256, 0, stream>>>(ei, ew, row_start, cursor, csr_pk);
    k_gbounds<<<1, N_B, 0, stream>>>(batch, gstart, gcnt);

    u16* hch = Hh0; u16* hcl = Hl0;
    u16* hnh = Hh1; u16* hnl = Hl1;
    for (int l = 0; l < 4; ++l) {
        k_agg<<<N_NODES / 8, 256, 0, stream>>>(hch, hcl, row_start, csr_pk, eps, l, Ah);
        k_mgemm1<<<dim3(MP / 128, 4), 256, 0, stream>>>(
            Ah, W1T + (size_t)l * H2_DIM * H_DIM,
            b1 + (size_t)l * H2_DIM, C1h);
        k_mgemm2<<<MP / 64, 256, 0, stream>>>(
            C1h, W2T + (size_t)l * H_DIM * H2_DIM,
            b2 + (size_t)l * H_DIM, ln_g + (size_t)l * H_DIM, ln_b + (size_t)l * H_DIM,
            hch, hcl, hnh, hnl);
        u16* th = hch; hch = hnh; hnh = th;
        u16* tl = hcl; hcl = hnl; hnl = tl;
    }

    k_pool<<<dim3(N_B, 4), 256, 0, stream>>>(hch, hcl, gstart, gcnt, gbuf);
    k_gene<<<N_B, 256, 0, stream>>>(gf, Wg1, bg1, lng_g, lng_b, Wg2, bg2, gbuf);
    k_cls<<<N_B, 256, 0, stream>>>(gbuf, Wc1, bc1, Wc2, bc2, Wc3, bc3, out);
}